// Round 1
// baseline (2000.855 us; speedup 1.0000x reference)
//
#include <hip/hip_runtime.h>

constexpr int kNodes = 100000;
constexpr int kEdges = 1600000;
constexpr int kDIn   = 256;
constexpr int kDEdge = 16;
constexpr int kDOut  = 128;

#define ROWS_PER_BLOCK 8
#define XSTRIDE 10   // pad stride (words) so float2 reads stay 8B-aligned, writes only 4-way conflict

// ---- Kernel 1: h_src = X @ W_neigh (-> ws); out = X @ W_self + b_self (-> d_out)
// 256 threads = 4 waves; 8 rows/block; 256 output cols (128 neigh | 128 self).
// thread: cg = t&63 -> 4 cols; rg = t>>6 -> 2 rows. LDS x-read is wave-uniform (broadcast).
__global__ __launch_bounds__(256) void fused_gemm(
    const float* __restrict__ X,
    const float* __restrict__ Wn,
    const float* __restrict__ Ws,
    const float* __restrict__ bs,
    float* __restrict__ h_src,
    float* __restrict__ out)
{
    __shared__ float xs[kDIn * XSTRIDE];
    const int t = threadIdx.x;               // t == k index for staging (256 == kDIn)
    const long row0 = (long)blockIdx.x * ROWS_PER_BLOCK;

    #pragma unroll
    for (int j = 0; j < ROWS_PER_BLOCK; ++j) {
        xs[t * XSTRIDE + j] = X[(row0 + j) * kDIn + t];   // coalesced global read
    }
    __syncthreads();

    const int cg = t & 63;
    const int rg = t >> 6;
    const int c0 = cg << 2;                  // [0,256)
    const int r0 = rg << 1;                  // {0,2,4,6}
    const bool selfh = (c0 >= kDOut);
    const float* W = selfh ? (Ws + (c0 - kDOut)) : (Wn + c0);

    float4 acc0 = {0.f, 0.f, 0.f, 0.f};
    float4 acc1 = {0.f, 0.f, 0.f, 0.f};

    #pragma unroll 8
    for (int k = 0; k < kDIn; ++k) {
        const float4 w = *(const float4*)(W + (size_t)k * kDOut);      // coalesced, L1/L2-hot
        const float2 x = *(const float2*)(xs + k * XSTRIDE + r0);      // wave-uniform broadcast
        acc0.x += x.x * w.x; acc0.y += x.x * w.y; acc0.z += x.x * w.z; acc0.w += x.x * w.w;
        acc1.x += x.y * w.x; acc1.y += x.y * w.y; acc1.z += x.y * w.z; acc1.w += x.y * w.w;
    }

    if (!selfh) {
        *(float4*)(h_src + (row0 + r0)     * kDOut + c0) = acc0;
        *(float4*)(h_src + (row0 + r0 + 1) * kDOut + c0) = acc1;
    } else {
        const int cs = c0 - kDOut;
        const float4 b = *(const float4*)(bs + cs);
        acc0.x += b.x; acc0.y += b.y; acc0.z += b.z; acc0.w += b.w;
        acc1.x += b.x; acc1.y += b.y; acc1.z += b.z; acc1.w += b.w;
        *(float4*)(out + (row0 + r0)     * kDOut + cs) = acc0;
        *(float4*)(out + (row0 + r0 + 1) * kDOut + cs) = acc1;
    }
}

// ---- Kernel 2: per edge e: acc[dst] += h_src[src] + X_edge[e] @ W_edge ; cnt[dst] += 1
// One wave per edge; lane handles 2 cols; fire-and-forget fp32 atomics.
__global__ __launch_bounds__(256) void edge_aggregate(
    const float* __restrict__ Xe,
    const int*   __restrict__ src,
    const int*   __restrict__ dst,
    const float* __restrict__ We,    // [16][128]
    const float* __restrict__ h_src,
    float* __restrict__ acc,
    float* __restrict__ cnt)
{
    __shared__ float wl[kDEdge * kDOut];     // 8 KB
    for (int i = threadIdx.x; i < kDEdge * kDOut; i += 256) wl[i] = We[i];
    __syncthreads();

    const int lane = threadIdx.x & 63;
    const int wv   = threadIdx.x >> 6;
    const int c    = lane << 1;

    for (long e = (long)blockIdx.x * 4 + wv; e < kEdges; e += (long)gridDim.x * 4) {
        const int s = src[e];
        const int d = dst[e];
        const float4* xe4 = (const float4*)(Xe + e * kDEdge);
        const float4 a0 = xe4[0], a1 = xe4[1], a2 = xe4[2], a3 = xe4[3];
        const float xe[16] = {a0.x,a0.y,a0.z,a0.w, a1.x,a1.y,a1.z,a1.w,
                              a2.x,a2.y,a2.z,a2.w, a3.x,a3.y,a3.z,a3.w};
        float ex = 0.f, ey = 0.f;
        #pragma unroll
        for (int k = 0; k < kDEdge; ++k) {   // fully unrolled -> static xe[] indices
            const float2 w = *(const float2*)(wl + k * kDOut + c);  // 2-way conflict = free
            ex += xe[k] * w.x;
            ey += xe[k] * w.y;
        }
        const float2 hs = *(const float2*)(h_src + (size_t)s * kDOut + c);  // L3-resident gather
        float* ap = acc + (size_t)d * kDOut + c;
        atomicAdd(ap,     ex + hs.x);
        atomicAdd(ap + 1, ey + hs.y);
        if (lane == 0) atomicAdd(cnt + d, 1.0f);
    }
}

// ---- Kernel 3: out += (cnt>0) ? acc/cnt : 0   (float4 grid-stride-free exact launch)
__global__ __launch_bounds__(256) void finalize(
    const float* __restrict__ acc,
    const float* __restrict__ cnt,
    float* __restrict__ out)
{
    const long i = (long)blockIdx.x * 256 + threadIdx.x;     // float4 index
    const long total = (long)kNodes * kDOut / 4;
    if (i >= total) return;
    const int n = (int)(i >> 5);                             // 32 float4 per node row
    const float cv = cnt[n];
    if (cv > 0.f) {
        const float inv = 1.0f / cv;
        float4 a = ((const float4*)acc)[i];
        float4 o = ((float4*)out)[i];
        o.x += a.x * inv; o.y += a.y * inv; o.z += a.z * inv; o.w += a.w * inv;
        ((float4*)out)[i] = o;
    }
}

extern "C" void kernel_launch(void* const* d_in, const int* in_sizes, int n_in,
                              void* d_out, int out_size, void* d_ws, size_t ws_size,
                              hipStream_t stream)
{
    const float* X  = (const float*)d_in[0];
    const float* Xe = (const float*)d_in[1];
    const float* Wn = (const float*)d_in[2];
    const float* Ws = (const float*)d_in[3];
    const float* bs = (const float*)d_in[4];
    const float* We = (const float*)d_in[5];
    const int*   src = (const int*)d_in[6];
    const int*   dst = (const int*)d_in[7];
    float* out = (float*)d_out;

    float* h_src = (float*)d_ws;                          // 100000*128 f32 = 51.2 MB
    float* acc   = h_src + (size_t)kNodes * kDOut;        // 51.2 MB
    float* cnt   = acc   + (size_t)kNodes * kDOut;        // 0.4 MB

    // zero acc + cnt (contiguous)
    hipMemsetAsync(acc, 0, ((size_t)kNodes * kDOut + kNodes) * sizeof(float), stream);

    fused_gemm<<<kNodes / ROWS_PER_BLOCK, 256, 0, stream>>>(X, Wn, Ws, bs, h_src, out);
    edge_aggregate<<<4096, 256, 0, stream>>>(Xe, src, dst, We, h_src, acc, cnt);
    finalize<<<(int)(((long)kNodes * kDOut / 4 + 255) / 256), 256, 0, stream>>>(acc, cnt, out);
}

// Round 2
// 881.094 us; speedup vs baseline: 2.2709x; 2.2709x over previous
//
#include <hip/hip_runtime.h>

constexpr int kNodes = 100000;
constexpr int kEdges = 1600000;
constexpr int kDIn   = 256;
constexpr int kDEdge = 16;
constexpr int kDOut  = 128;

constexpr int kChunk  = 256;
constexpr int kNChunk = (kNodes + kChunk - 1) / kChunk;   // 391

// ---- Kernel 1: h_src = X @ W_neigh (-> ws); out = X @ W_self + b_self (-> d_out)
// 256 threads = 4 waves; 16 rows/block. lane -> 4 cols (c0 = (t&63)*4 over 256 cols:
// [0,128) neigh, [128,256) self). wave -> 4 rows. LDS x-reads are wave-uniform broadcasts.
#define ROWS 16
#define XPAD 20   // floats per k-row; 80B stride keeps float4 reads 16B-aligned

__global__ __launch_bounds__(256) void fused_gemm(
    const float* __restrict__ X,
    const float* __restrict__ Wn,
    const float* __restrict__ Ws,
    const float* __restrict__ bs,
    float* __restrict__ h_src,
    float* __restrict__ out)
{
    __shared__ float xs[kDIn * XPAD];            // 20 KB
    const int t = threadIdx.x;                   // t == k index while staging
    const long row0 = (long)blockIdx.x * ROWS;

    #pragma unroll
    for (int j = 0; j < ROWS; ++j)
        xs[t * XPAD + j] = X[(row0 + j) * kDIn + t];   // coalesced
    __syncthreads();

    const int c0 = (t & 63) << 2;
    const int r0 = (t >> 6) << 2;
    const bool selfh = (c0 >= kDOut);
    const float* W = selfh ? (Ws + (c0 - kDOut)) : (Wn + c0);

    float4 a0{0,0,0,0}, a1{0,0,0,0}, a2{0,0,0,0}, a3{0,0,0,0};

    #pragma unroll 4
    for (int k = 0; k < kDIn; ++k) {
        const float4 w = *(const float4*)(W + (size_t)k * kDOut);
        const float4 x = *(const float4*)(xs + k * XPAD + r0);   // wave-uniform broadcast
        a0.x += x.x*w.x; a0.y += x.x*w.y; a0.z += x.x*w.z; a0.w += x.x*w.w;
        a1.x += x.y*w.x; a1.y += x.y*w.y; a1.z += x.y*w.z; a1.w += x.y*w.w;
        a2.x += x.z*w.x; a2.y += x.z*w.y; a2.z += x.z*w.z; a2.w += x.z*w.w;
        a3.x += x.w*w.x; a3.y += x.w*w.y; a3.z += x.w*w.z; a3.w += x.w*w.w;
    }

    if (!selfh) {
        float* p = h_src + (row0 + r0) * kDOut + c0;
        *(float4*)(p)            = a0;
        *(float4*)(p + kDOut)    = a1;
        *(float4*)(p + 2*kDOut)  = a2;
        *(float4*)(p + 3*kDOut)  = a3;
    } else {
        const int cs = c0 - kDOut;
        const float4 b = *(const float4*)(bs + cs);
        a0.x+=b.x; a0.y+=b.y; a0.z+=b.z; a0.w+=b.w;
        a1.x+=b.x; a1.y+=b.y; a1.z+=b.z; a1.w+=b.w;
        a2.x+=b.x; a2.y+=b.y; a2.z+=b.z; a2.w+=b.w;
        a3.x+=b.x; a3.y+=b.y; a3.z+=b.z; a3.w+=b.w;
        float* p = out + (row0 + r0) * kDOut + cs;
        *(float4*)(p)            = a0;
        *(float4*)(p + kDOut)    = a1;
        *(float4*)(p + 2*kDOut)  = a2;
        *(float4*)(p + 3*kDOut)  = a3;
    }
}

// ---- CSR construction ----
__global__ __launch_bounds__(256) void hist(const int* __restrict__ dst,
                                            int* __restrict__ count)
{
    const int e = blockIdx.x * 256 + threadIdx.x;
    if (e < kEdges) atomicAdd(&count[dst[e]], 1);
}

__global__ __launch_bounds__(256) void chunk_sum(const int* __restrict__ count,
                                                 int* __restrict__ partial)
{
    __shared__ int s[256];
    const int i = blockIdx.x * 256 + threadIdx.x;
    s[threadIdx.x] = (i < kNodes) ? count[i] : 0;
    __syncthreads();
    for (int off = 128; off > 0; off >>= 1) {
        if (threadIdx.x < off) s[threadIdx.x] += s[threadIdx.x + off];
        __syncthreads();
    }
    if (threadIdx.x == 0) partial[blockIdx.x] = s[0];
}

__global__ __launch_bounds__(512) void scan_partial(int* __restrict__ partial)
{
    __shared__ int s[512];
    const int t = threadIdx.x;
    const int v = (t < kNChunk) ? partial[t] : 0;
    s[t] = v;
    __syncthreads();
    for (int off = 1; off < 512; off <<= 1) {
        const int u = (t >= off) ? s[t - off] : 0;
        __syncthreads();
        s[t] += u;
        __syncthreads();
    }
    if (t < kNChunk) partial[t] = s[t] - v;     // exclusive prefix of chunk sums
}

__global__ __launch_bounds__(256) void make_row_start(const int* __restrict__ count,
                                                      const int* __restrict__ partial,
                                                      int* __restrict__ row_start)
{
    __shared__ int s[256];
    const int t = threadIdx.x;
    const int i = blockIdx.x * 256 + t;
    const int v = (i < kNodes) ? count[i] : 0;
    s[t] = v;
    __syncthreads();
    for (int off = 1; off < 256; off <<= 1) {
        const int u = (t >= off) ? s[t - off] : 0;
        __syncthreads();
        s[t] += u;
        __syncthreads();
    }
    if (i < kNodes) row_start[i] = partial[blockIdx.x] + s[t] - v;
}

__global__ __launch_bounds__(256) void scatter(const int* __restrict__ dst,
                                               const int* __restrict__ row_start,
                                               int* __restrict__ cursor,
                                               int* __restrict__ bucket)
{
    const int e = blockIdx.x * 256 + threadIdx.x;
    if (e < kEdges) {
        const int d = dst[e];
        const int pos = row_start[d] + atomicAdd(&cursor[d], 1);
        bucket[pos] = e;
    }
}

// ---- Kernel 5: pull-aggregate. One wave per node; lane owns 2 output cols.
// W_edge lives in 32 VGPRs; edge/src ids via readfirstlane -> scalar loads.
__global__ __launch_bounds__(256) void aggregate(
    const float* __restrict__ Xe,
    const int*   __restrict__ src,
    const float* __restrict__ We,
    const float* __restrict__ h_src,
    const int*   __restrict__ count,
    const int*   __restrict__ row_start,
    const int*   __restrict__ bucket,
    float* __restrict__ out)
{
    const int lane = threadIdx.x & 63;
    const int wv   = threadIdx.x >> 6;
    const int c    = lane << 1;

    float2 we[kDEdge];
    #pragma unroll
    for (int k = 0; k < kDEdge; ++k)
        we[k] = *(const float2*)(We + k * kDOut + c);

    const int n = blockIdx.x * 4 + wv;
    if (n >= kNodes) return;
    const int deg = count[n];
    if (deg == 0) return;
    const int base = row_start[n];

    float ax = 0.f, ay = 0.f;
    for (int i = 0; i < deg; ++i) {
        const int e = __builtin_amdgcn_readfirstlane(bucket[base + i]);
        const int s = __builtin_amdgcn_readfirstlane(src[e]);
        const float* xe = Xe + (size_t)e * kDEdge;          // uniform -> s_load
        const float2 hs = *(const float2*)(h_src + (size_t)s * kDOut + c);
        float px = hs.x, py = hs.y;
        #pragma unroll
        for (int k = 0; k < kDEdge; ++k) {
            const float xv = xe[k];
            px += xv * we[k].x;
            py += xv * we[k].y;
        }
        ax += px; ay += py;
    }

    const float inv = 1.0f / (float)deg;
    float2* op = (float2*)(out + (size_t)n * kDOut + c);
    float2 o = *op;
    o.x += ax * inv;
    o.y += ay * inv;
    *op = o;
}

extern "C" void kernel_launch(void* const* d_in, const int* in_sizes, int n_in,
                              void* d_out, int out_size, void* d_ws, size_t ws_size,
                              hipStream_t stream)
{
    const float* X  = (const float*)d_in[0];
    const float* Xe = (const float*)d_in[1];
    const float* Wn = (const float*)d_in[2];
    const float* Ws = (const float*)d_in[3];
    const float* bs = (const float*)d_in[4];
    const float* We = (const float*)d_in[5];
    const int*   srcp = (const int*)d_in[6];
    const int*   dstp = (const int*)d_in[7];
    float* out = (float*)d_out;

    float* h_src    = (float*)d_ws;                                  // 51.2 MB
    int*   count    = (int*)(h_src + (size_t)kNodes * kDOut);        // 400 KB
    int*   cursor   = count + kNodes;                                // 400 KB (memset with count)
    int*   row_s    = cursor + kNodes;                               // 400 KB
    int*   partial  = row_s + kNodes;                                // 2 KB
    int*   bucket   = partial + 512;                                 // 6.4 MB

    hipMemsetAsync(count, 0, 2 * (size_t)kNodes * sizeof(int), stream);

    fused_gemm<<<kNodes / ROWS, 256, 0, stream>>>(X, Wn, Ws, bs, h_src, out);

    const int eb = (kEdges + 255) / 256;
    hist<<<eb, 256, 0, stream>>>(dstp, count);
    chunk_sum<<<kNChunk, 256, 0, stream>>>(count, partial);
    scan_partial<<<1, 512, 0, stream>>>(partial);
    make_row_start<<<kNChunk, 256, 0, stream>>>(count, partial, row_s);
    scatter<<<eb, 256, 0, stream>>>(dstp, row_s, cursor, bucket);

    aggregate<<<(kNodes + 3) / 4, 256, 0, stream>>>(Xe, srcp, We, h_src,
                                                    count, row_s, bucket, out);
}

// Round 3
// 781.240 us; speedup vs baseline: 2.5611x; 1.1278x over previous
//
#include <hip/hip_runtime.h>
#include <stdint.h>

constexpr int kNodes = 100000;
constexpr int kEdges = 1600000;
constexpr int kDIn   = 256;
constexpr int kDEdge = 16;
constexpr int kDOut  = 128;

constexpr int kChunk  = 256;
constexpr int kNChunk = (kNodes + kChunk - 1) / kChunk;   // 391

typedef short  short8 __attribute__((ext_vector_type(8)));
typedef __bf16 bf16x8 __attribute__((ext_vector_type(8)));
typedef float  f32x4  __attribute__((ext_vector_type(4)));

union Frag { short8 s; bf16x8 b; };

static __device__ __forceinline__ ushort f2bf(float f) {
    uint32_t u = __builtin_bit_cast(uint32_t, f);
    u += 0x7FFFu + ((u >> 16) & 1u);          // RNE
    return (ushort)(u >> 16);
}

// ---- prep_w: W_neigh|W_self -> bf16, transposed to [n][k], pre-swizzled so the
// GEMM's B-staging is a LINEAR global_load_lds and the swizzled ds_read matches.
// Unit u: n = u&255, kc = (u>>8)&3, step = u>>10. LDS byte q = (n*64+kc*16)^((n&7)<<4).
__global__ __launch_bounds__(256) void prep_w(const float* __restrict__ Wn,
                                              const float* __restrict__ Ws,
                                              char* __restrict__ Wstage)
{
    const int u = blockIdx.x * 256 + threadIdx.x;        // 8192 units
    const int n = u & 255, kc = (u >> 8) & 3, step = u >> 10;
    const float* wp = (n < kDOut) ? (Wn + n) : (Ws + (n - kDOut));
    const int k0 = step * 32 + kc * 8;
    short8 v;
    #pragma unroll
    for (int j = 0; j < 8; ++j)
        v[j] = (short)f2bf(wp[(size_t)(k0 + j) * kDOut]);
    const int q = (n * 64 + kc * 16) ^ ((n & 7) << 4);
    *(short8*)(Wstage + (size_t)step * 16384 + q) = v;
}

// ---- mfma_gemm: [h_src | out] = X @ [Wn | Ws] (+ b_self on self half), bf16 MFMA.
// 782 blocks x 512 threads (8 waves, 2Mx4N of 64x64). BM=128, BN=256, BK=32, 8 K-steps.
// A: [128][32] bf16 LDS (reg-staged, XOR swizzle (r&7)<<4 on 64B rows).
// B: [256][32] bf16 LDS (global_load_lds from pre-swizzled Wstage).
__global__ __launch_bounds__(512) void mfma_gemm(
    const float* __restrict__ X,
    const char*  __restrict__ Wstage,
    const float* __restrict__ bs,
    float* __restrict__ h_src,
    float* __restrict__ out)
{
    __shared__ char lds[24576];              // A: [0,8192)  B: [8192,24576)
    const int t    = threadIdx.x;
    const int lane = t & 63, wid = t >> 6;
    const int wr   = wid >> 2, wc = wid & 3;
    const int l15  = lane & 15;
    const int kb   = (lane >> 4) << 4;       // k-chunk byte offset (0/16/32/48)
    const long row0 = (long)blockIdx.x * 128;

    // A staging: thread -> (row ar, k-slot as); 8 consecutive k per slot
    const int ar = t >> 2;
    const int as = t & 3;
    long arow = row0 + ar; if (arow > kNodes - 1) arow = kNodes - 1;   // clamp tail
    const float4* xg = (const float4*)(X + arow * kDIn);
    char* aw = lds + ((ar * 64 + as * 16) ^ ((ar & 7) << 4));

    // fragment read addresses (constant across K-steps)
    const int aswz   = (l15 & 7) << 4;
    const int addrA0 = ((wr * 64 + l15) * 64 + kb) ^ aswz;
    const int addrB0 = ((((wc * 64 + l15) * 64) + kb) ^ aswz) + 8192;

    f32x4 acc[4][4] = {};

    for (int step = 0; step < 8; ++step) {
        // B tile: linear copy (dest = uniform base + lane*16)
        {
            const char* g = Wstage + (size_t)step * 16384 + wid * 2048 + lane * 16;
            char* l = lds + 8192 + wid * 2048;
            __builtin_amdgcn_global_load_lds(
                (const __attribute__((address_space(1))) uint32_t*)g,
                (__attribute__((address_space(3))) uint32_t*)l, 16, 0, 0);
            __builtin_amdgcn_global_load_lds(
                (const __attribute__((address_space(1))) uint32_t*)(g + 1024),
                (__attribute__((address_space(3))) uint32_t*)(l + 1024), 16, 0, 0);
        }
        // A tile: fp32 -> bf16 -> swizzled ds_write_b128
        const float4 f0 = xg[step * 8 + as * 2];
        const float4 f1 = xg[step * 8 + as * 2 + 1];
        short8 av;
        av[0] = (short)f2bf(f0.x); av[1] = (short)f2bf(f0.y);
        av[2] = (short)f2bf(f0.z); av[3] = (short)f2bf(f0.w);
        av[4] = (short)f2bf(f1.x); av[5] = (short)f2bf(f1.y);
        av[6] = (short)f2bf(f1.z); av[7] = (short)f2bf(f1.w);
        *(short8*)aw = av;
        __syncthreads();                     // drains vmcnt+lgkm, then barrier

        Frag af[4], bf[4];
        #pragma unroll
        for (int m = 0; m < 4; ++m) af[m].s = *(const short8*)(lds + addrA0 + m * 1024);
        #pragma unroll
        for (int n = 0; n < 4; ++n) bf[n].s = *(const short8*)(lds + addrB0 + n * 1024);
        #pragma unroll
        for (int m = 0; m < 4; ++m)
            #pragma unroll
            for (int n = 0; n < 4; ++n)
                acc[m][n] = __builtin_amdgcn_mfma_f32_16x16x32_bf16(af[m].b, bf[n].b, acc[m][n], 0, 0, 0);
        __syncthreads();                     // protect LDS before next overwrite
    }

    // epilogue: C/D layout col=lane&15, row=(lane>>4)*4+j  [m89]
    const int rb = (lane >> 4) << 2;
    #pragma unroll
    for (int n = 0; n < 4; ++n) {
        const int col = wc * 64 + n * 16 + l15;          // [0,256)
        const bool selfh = (col >= kDOut);
        const int c = selfh ? (col - kDOut) : col;
        const float bias = selfh ? bs[c] : 0.0f;
        float* dp = selfh ? out : h_src;
        #pragma unroll
        for (int m = 0; m < 4; ++m) {
            const long r = row0 + wr * 64 + m * 16 + rb;
            #pragma unroll
            for (int j = 0; j < 4; ++j) {
                if (r + j < kNodes)
                    dp[(r + j) * kDOut + c] = acc[m][n][j] + bias;
            }
        }
    }
}

// ---- CSR construction ----
__global__ __launch_bounds__(256) void hist(const int* __restrict__ dst,
                                            int* __restrict__ count)
{
    const int e = blockIdx.x * 256 + threadIdx.x;
    if (e < kEdges) atomicAdd(&count[dst[e]], 1);
}

__global__ __launch_bounds__(256) void chunk_sum(const int* __restrict__ count,
                                                 int* __restrict__ partial)
{
    __shared__ int s[256];
    const int i = blockIdx.x * 256 + threadIdx.x;
    s[threadIdx.x] = (i < kNodes) ? count[i] : 0;
    __syncthreads();
    for (int off = 128; off > 0; off >>= 1) {
        if (threadIdx.x < off) s[threadIdx.x] += s[threadIdx.x + off];
        __syncthreads();
    }
    if (threadIdx.x == 0) partial[blockIdx.x] = s[0];
}

__global__ __launch_bounds__(512) void scan_partial(int* __restrict__ partial)
{
    __shared__ int s[512];
    const int t = threadIdx.x;
    const int v = (t < kNChunk) ? partial[t] : 0;
    s[t] = v;
    __syncthreads();
    for (int off = 1; off < 512; off <<= 1) {
        const int u = (t >= off) ? s[t - off] : 0;
        __syncthreads();
        s[t] += u;
        __syncthreads();
    }
    if (t < kNChunk) partial[t] = s[t] - v;
}

__global__ __launch_bounds__(256) void make_row_start(const int* __restrict__ count,
                                                      const int* __restrict__ partial,
                                                      int* __restrict__ row_start)
{
    __shared__ int s[256];
    const int t = threadIdx.x;
    const int i = blockIdx.x * 256 + t;
    const int v = (i < kNodes) ? count[i] : 0;
    s[t] = v;
    __syncthreads();
    for (int off = 1; off < 256; off <<= 1) {
        const int u = (t >= off) ? s[t - off] : 0;
        __syncthreads();
        s[t] += u;
        __syncthreads();
    }
    if (i < kNodes) row_start[i] = partial[blockIdx.x] + s[t] - v;
}

__global__ __launch_bounds__(256) void scatter(const int* __restrict__ dst,
                                               const int* __restrict__ row_start,
                                               int* __restrict__ cursor,
                                               int* __restrict__ bucket)
{
    const int e = blockIdx.x * 256 + threadIdx.x;
    if (e < kEdges) {
        const int d = dst[e];
        const int pos = row_start[d] + atomicAdd(&cursor[d], 1);
        bucket[pos] = e;
    }
}

// ---- aggregate: one wave per node; lanes 0..15 prefetch 16 edge/src ids, inner
// loop gets them via __shfl so the h_src gathers are independent (MLP, not a
// serial dependent chain).
__global__ __launch_bounds__(256) void aggregate(
    const float* __restrict__ Xe,
    const int*   __restrict__ src,
    const float* __restrict__ We,
    const float* __restrict__ h_src,
    const int*   __restrict__ count,
    const int*   __restrict__ row_start,
    const int*   __restrict__ bucket,
    float* __restrict__ out)
{
    const int lane = threadIdx.x & 63;
    const int wv   = threadIdx.x >> 6;
    const int c    = lane << 1;

    float2 we[kDEdge];
    #pragma unroll
    for (int k = 0; k < kDEdge; ++k)
        we[k] = *(const float2*)(We + k * kDOut + c);

    const int n = blockIdx.x * 4 + wv;
    if (n >= kNodes) return;
    const int deg = count[n];
    if (deg == 0) return;
    const int base = row_start[n];

    float ax = 0.f, ay = 0.f;
    for (int i0 = 0; i0 < deg; i0 += 16) {
        const int m = min(16, deg - i0);
        int e_l = 0, s_l = 0;
        if (lane < m) {
            e_l = bucket[base + i0 + lane];
            s_l = src[e_l];
        }
        for (int j = 0; j < m; ++j) {
            const int e = __shfl(e_l, j);
            const int s = __shfl(s_l, j);
            const float4* xe4 = (const float4*)(Xe + (size_t)e * kDEdge);
            const float2 hs = *(const float2*)(h_src + (size_t)s * kDOut + c);
            const float4 a0 = xe4[0], a1 = xe4[1], a2 = xe4[2], a3 = xe4[3];
            const float xv[16] = {a0.x,a0.y,a0.z,a0.w, a1.x,a1.y,a1.z,a1.w,
                                  a2.x,a2.y,a2.z,a2.w, a3.x,a3.y,a3.z,a3.w};
            float px = hs.x, py = hs.y;
            #pragma unroll
            for (int k = 0; k < kDEdge; ++k) {
                px += xv[k] * we[k].x;
                py += xv[k] * we[k].y;
            }
            ax += px; ay += py;
        }
    }

    const float inv = 1.0f / (float)deg;
    float2* op = (float2*)(out + (size_t)n * kDOut + c);
    float2 o = *op;
    o.x += ax * inv;
    o.y += ay * inv;
    *op = o;
}

extern "C" void kernel_launch(void* const* d_in, const int* in_sizes, int n_in,
                              void* d_out, int out_size, void* d_ws, size_t ws_size,
                              hipStream_t stream)
{
    const float* X  = (const float*)d_in[0];
    const float* Xe = (const float*)d_in[1];
    const float* Wn = (const float*)d_in[2];
    const float* Ws = (const float*)d_in[3];
    const float* bs = (const float*)d_in[4];
    const float* We = (const float*)d_in[5];
    const int*   srcp = (const int*)d_in[6];
    const int*   dstp = (const int*)d_in[7];
    float* out = (float*)d_out;

    float* h_src  = (float*)d_ws;                                 // 51.2 MB
    char*  Wstage = (char*)(h_src + (size_t)kNodes * kDOut);      // 128 KB
    int*   count  = (int*)(Wstage + 8 * 16384);                   // 400 KB
    int*   cursor = count + kNodes;                               // 400 KB
    int*   row_s  = cursor + kNodes;                              // 400 KB
    int*   partial = row_s + kNodes;                              // 2 KB
    int*   bucket  = partial + 512;                               // 6.4 MB

    hipMemsetAsync(count, 0, 2 * (size_t)kNodes * sizeof(int), stream);

    prep_w<<<32, 256, 0, stream>>>(Wn, Ws, Wstage);
    mfma_gemm<<<(kNodes + 127) / 128, 512, 0, stream>>>(X, Wstage, bs, h_src, out);

    const int eb = (kEdges + 255) / 256;
    hist<<<eb, 256, 0, stream>>>(dstp, count);
    chunk_sum<<<kNChunk, 256, 0, stream>>>(count, partial);
    scan_partial<<<1, 512, 0, stream>>>(partial);
    make_row_start<<<kNChunk, 256, 0, stream>>>(count, partial, row_s);
    scatter<<<eb, 256, 0, stream>>>(dstp, row_s, cursor, bucket);

    aggregate<<<(kNodes + 3) / 4, 256, 0, stream>>>(Xe, srcp, We, h_src,
                                                    count, row_s, bucket, out);
}

// Round 5
// 570.740 us; speedup vs baseline: 3.5057x; 1.3688x over previous
//
#include <hip/hip_runtime.h>
#include <stdint.h>

constexpr int kNodes = 100000;
constexpr int kEdges = 1600000;
constexpr int kDIn   = 256;
constexpr int kDEdge = 16;
constexpr int kDOut  = 128;

constexpr int kChunk  = 256;
constexpr int kNChunk = (kNodes + kChunk - 1) / kChunk;   // 391

typedef short  short8 __attribute__((ext_vector_type(8)));
typedef __bf16 bf16x8 __attribute__((ext_vector_type(8)));
typedef float  f32x4  __attribute__((ext_vector_type(4)));

union Frag { short8 s; bf16x8 b; };

static __device__ __forceinline__ ushort f2bf(float f) {
    uint32_t u = __builtin_bit_cast(uint32_t, f);
    u += 0x7FFFu + ((u >> 16) & 1u);          // RNE
    return (ushort)(u >> 16);
}
static __device__ __forceinline__ float bflo(uint32_t u) {
    return __builtin_bit_cast(float, u << 16);
}
static __device__ __forceinline__ float bfhi(uint32_t u) {
    return __builtin_bit_cast(float, u & 0xFFFF0000u);
}

// ---- prep_w: W_neigh|W_self -> bf16, transposed to [n][k], pre-swizzled so the
// GEMM's B-staging is a LINEAR global_load_lds and the swizzled ds_read matches.
__global__ __launch_bounds__(256) void prep_w(const float* __restrict__ Wn,
                                              const float* __restrict__ Ws,
                                              char* __restrict__ Wstage)
{
    const int u = blockIdx.x * 256 + threadIdx.x;        // 8192 units
    const int n = u & 255, kc = (u >> 8) & 3, step = u >> 10;
    const float* wp = (n < kDOut) ? (Wn + n) : (Ws + (n - kDOut));
    const int k0 = step * 32 + kc * 8;
    short8 v;
    #pragma unroll
    for (int j = 0; j < 8; ++j)
        v[j] = (short)f2bf(wp[(size_t)(k0 + j) * kDOut]);
    const int q = (n * 64 + kc * 16) ^ ((n & 7) << 4);
    *(short8*)(Wstage + (size_t)step * 16384 + q) = v;
}

// ---- mfma_gemm: h_src(bf16) = X @ Wn ; out(f32) = X @ Ws + b_self.
// 782 blocks x 512 threads (8 waves, 2Mx4N of 64x64). BM=128, BN=256, BK=32.
__global__ __launch_bounds__(512) void mfma_gemm(
    const float* __restrict__ X,
    const char*  __restrict__ Wstage,
    const float* __restrict__ bs,
    ushort* __restrict__ h_srcb,
    float* __restrict__ out)
{
    __shared__ char lds[24576];              // A: [0,8192)  B: [8192,24576)
    const int t    = threadIdx.x;
    const int lane = t & 63, wid = t >> 6;
    const int wr   = wid >> 2, wc = wid & 3;
    const int l15  = lane & 15;
    const int kb   = (lane >> 4) << 4;
    const long row0 = (long)blockIdx.x * 128;

    const int ar = t >> 2;
    const int as = t & 3;
    long arow = row0 + ar; if (arow > kNodes - 1) arow = kNodes - 1;
    const float4* xg = (const float4*)(X + arow * kDIn);
    char* aw = lds + ((ar * 64 + as * 16) ^ ((ar & 7) << 4));

    const int aswz   = (l15 & 7) << 4;
    const int addrA0 = ((wr * 64 + l15) * 64 + kb) ^ aswz;
    const int addrB0 = ((((wc * 64 + l15) * 64) + kb) ^ aswz) + 8192;

    f32x4 acc[4][4] = {};

    for (int step = 0; step < 8; ++step) {
        {
            const char* g = Wstage + (size_t)step * 16384 + wid * 2048 + lane * 16;
            char* l = lds + 8192 + wid * 2048;
            __builtin_amdgcn_global_load_lds(
                (const __attribute__((address_space(1))) uint32_t*)g,
                (__attribute__((address_space(3))) uint32_t*)l, 16, 0, 0);
            __builtin_amdgcn_global_load_lds(
                (const __attribute__((address_space(1))) uint32_t*)(g + 1024),
                (__attribute__((address_space(3))) uint32_t*)(l + 1024), 16, 0, 0);
        }
        const float4 f0 = xg[step * 8 + as * 2];
        const float4 f1 = xg[step * 8 + as * 2 + 1];
        short8 av;
        av[0] = (short)f2bf(f0.x); av[1] = (short)f2bf(f0.y);
        av[2] = (short)f2bf(f0.z); av[3] = (short)f2bf(f0.w);
        av[4] = (short)f2bf(f1.x); av[5] = (short)f2bf(f1.y);
        av[6] = (short)f2bf(f1.z); av[7] = (short)f2bf(f1.w);
        *(short8*)aw = av;
        __syncthreads();

        Frag af[4], bf[4];
        #pragma unroll
        for (int m = 0; m < 4; ++m) af[m].s = *(const short8*)(lds + addrA0 + m * 1024);
        #pragma unroll
        for (int n = 0; n < 4; ++n) bf[n].s = *(const short8*)(lds + addrB0 + n * 1024);
        #pragma unroll
        for (int m = 0; m < 4; ++m)
            #pragma unroll
            for (int n = 0; n < 4; ++n)
                acc[m][n] = __builtin_amdgcn_mfma_f32_16x16x32_bf16(af[m].b, bf[n].b, acc[m][n], 0, 0, 0);
        __syncthreads();
    }

    // epilogue: C/D layout col=lane&15, row=(lane>>4)*4+j
    const int rb = (lane >> 4) << 2;
    #pragma unroll
    for (int n = 0; n < 4; ++n) {
        const int col = wc * 64 + n * 16 + l15;          // [0,256)
        const bool selfh = (col >= kDOut);
        const int c = selfh ? (col - kDOut) : col;
        const float bias = selfh ? bs[c] : 0.0f;
        #pragma unroll
        for (int m = 0; m < 4; ++m) {
            const long r = row0 + wr * 64 + m * 16 + rb;
            #pragma unroll
            for (int j = 0; j < 4; ++j) {
                if (r + j < kNodes) {
                    if (selfh) out[(r + j) * kDOut + c] = acc[m][n][j] + bias;
                    else       h_srcb[(r + j) * kDOut + c] = f2bf(acc[m][n][j]);
                }
            }
        }
    }
}

// ---- CSR construction ----
__global__ __launch_bounds__(256) void hist(const int* __restrict__ dst,
                                            int* __restrict__ count)
{
    const int e = blockIdx.x * 256 + threadIdx.x;
    if (e < kEdges) atomicAdd(&count[dst[e]], 1);
}

__global__ __launch_bounds__(256) void chunk_sum(const int* __restrict__ count,
                                                 int* __restrict__ partial)
{
    __shared__ int s[256];
    const int i = blockIdx.x * 256 + threadIdx.x;
    s[threadIdx.x] = (i < kNodes) ? count[i] : 0;
    __syncthreads();
    for (int off = 128; off > 0; off >>= 1) {
        if (threadIdx.x < off) s[threadIdx.x] += s[threadIdx.x + off];
        __syncthreads();
    }
    if (threadIdx.x == 0) partial[blockIdx.x] = s[0];
}

__global__ __launch_bounds__(512) void scan_partial(int* __restrict__ partial)
{
    __shared__ int s[512];
    const int t = threadIdx.x;
    const int v = (t < kNChunk) ? partial[t] : 0;
    s[t] = v;
    __syncthreads();
    for (int off = 1; off < 512; off <<= 1) {
        const int u = (t >= off) ? s[t - off] : 0;
        __syncthreads();
        s[t] += u;
        __syncthreads();
    }
    if (t < kNChunk) partial[t] = s[t] - v;
}

__global__ __launch_bounds__(256) void make_row_start(const int* __restrict__ count,
                                                      const int* __restrict__ partial,
                                                      int* __restrict__ row_start)
{
    __shared__ int s[256];
    const int t = threadIdx.x;
    const int i = blockIdx.x * 256 + t;
    const int v = (i < kNodes) ? count[i] : 0;
    s[t] = v;
    __syncthreads();
    for (int off = 1; off < 256; off <<= 1) {
        const int u = (t >= off) ? s[t - off] : 0;
        __syncthreads();
        s[t] += u;
        __syncthreads();
    }
    if (i < kNodes) row_start[i] = partial[blockIdx.x] + s[t] - v;
}

__global__ __launch_bounds__(256) void scatter(const int* __restrict__ dst,
                                               const int* __restrict__ row_start,
                                               int* __restrict__ cursor,
                                               int* __restrict__ bucket)
{
    const int e = blockIdx.x * 256 + threadIdx.x;
    if (e < kEdges) {
        const int d = dst[e];
        const int pos = row_start[d] + atomicAdd(&cursor[d], 1);
        bucket[pos] = e;
    }
}

// ---- aggregate: one wave per node.
// Per 16-edge batch: lanes 0..15 fetch edge/src ids; Xe is covered EXACTLY ONCE
// by the 64 lanes (lane -> edge lane>>2, chunk lane&3); per edge, each lane
// gathers its 2 bf16 h_src cols (1 dword). Edge features are only SUMMED; the
// 16x128 We matvec is applied once per node at the end (linearity).
__global__ __launch_bounds__(256) void aggregate(
    const float*  __restrict__ Xe,
    const int*    __restrict__ src,
    const float*  __restrict__ We,
    const ushort* __restrict__ h_srcb,
    const int*    __restrict__ count,
    const int*    __restrict__ row_start,
    const int*    __restrict__ bucket,
    float* __restrict__ out)
{
    const int lane = threadIdx.x & 63;
    const int wv   = threadIdx.x >> 6;
    const int c    = lane << 1;

    const int n = blockIdx.x * 4 + wv;
    if (n >= kNodes) return;
    const int deg = count[n];
    if (deg == 0) return;
    const int base = row_start[n];
    const int ch = (lane & 3) << 2;          // this lane's Xe chunk base k
    const int je = lane >> 2;                // this lane's edge slot for Xe

    float ax = 0.f, ay = 0.f;
    float4 xs{0.f, 0.f, 0.f, 0.f};

    for (int i0 = 0; i0 < deg; i0 += 16) {
        const int m = min(16, deg - i0);
        int e_l = 0, s_l = 0;
        if (lane < m) {
            e_l = bucket[base + i0 + lane];
            s_l = src[e_l];
        }
        // Xe sum: 64 lanes cover 16 edges x 4 chunks exactly once
        const int eb = __shfl(e_l, je);
        if (je < m) {
            const float4 x0 = *(const float4*)(Xe + (size_t)eb * kDEdge + ch);
            xs.x += x0.x; xs.y += x0.y; xs.z += x0.z; xs.w += x0.w;
        }
        // h_src gather: one dword per lane per edge
        int j = 0;
        for (; j + 1 < m; j += 2) {
            const int s0 = __shfl(s_l, j);
            const int s1 = __shfl(s_l, j + 1);
            const uint32_t h0 = *(const uint32_t*)(h_srcb + (size_t)s0 * kDOut + c);
            const uint32_t h1 = *(const uint32_t*)(h_srcb + (size_t)s1 * kDOut + c);
            ax += bflo(h0) + bflo(h1);
            ay += bfhi(h0) + bfhi(h1);
        }
        if (j < m) {
            const int s0 = __shfl(s_l, j);
            const uint32_t h0 = *(const uint32_t*)(h_srcb + (size_t)s0 * kDOut + c);
            ax += bflo(h0);
            ay += bfhi(h0);
        }
    }

    // reduce xs over the 16 lanes sharing lane&3 (16 distinct edges each batch)
    #pragma unroll
    for (int mask = 4; mask < 64; mask <<= 1) {
        xs.x += __shfl_xor(xs.x, mask);
        xs.y += __shfl_xor(xs.y, mask);
        xs.z += __shfl_xor(xs.z, mask);
        xs.w += __shfl_xor(xs.w, mask);
    }
    // broadcast chunk q from lane q (lane q has lane&3 == q for q<4)
    float xesum[kDEdge];
    #pragma unroll
    for (int q = 0; q < 4; ++q) {
        xesum[q * 4 + 0] = __shfl(xs.x, q);
        xesum[q * 4 + 1] = __shfl(xs.y, q);
        xesum[q * 4 + 2] = __shfl(xs.z, q);
        xesum[q * 4 + 3] = __shfl(xs.w, q);
    }

    // one 16x128 matvec: p = (sum Xe) @ We, this lane's 2 cols
    float px = 0.f, py = 0.f;
    #pragma unroll
    for (int k = 0; k < kDEdge; ++k) {
        const float2 w = *(const float2*)(We + k * kDOut + c);
        px += xesum[k] * w.x;
        py += xesum[k] * w.y;
    }

    const float inv = 1.0f / (float)deg;
    float2* op = (float2*)(out + (size_t)n * kDOut + c);
    float2 o = *op;
    o.x += (ax + px) * inv;
    o.y += (ay + py) * inv;
    *op = o;
}

extern "C" void kernel_launch(void* const* d_in, const int* in_sizes, int n_in,
                              void* d_out, int out_size, void* d_ws, size_t ws_size,
                              hipStream_t stream)
{
    const float* X  = (const float*)d_in[0];
    const float* Xe = (const float*)d_in[1];
    const float* Wn = (const float*)d_in[2];
    const float* Ws = (const float*)d_in[3];
    const float* bs = (const float*)d_in[4];
    const float* We = (const float*)d_in[5];
    const int*   srcp = (const int*)d_in[6];
    const int*   dstp = (const int*)d_in[7];
    float* out = (float*)d_out;

    ushort* h_srcb = (ushort*)d_ws;                               // 25.6 MB
    char*  Wstage  = (char*)(h_srcb + (size_t)kNodes * kDOut);    // 128 KB
    int*   count   = (int*)(Wstage + 8 * 16384);                  // 400 KB
    int*   cursor  = count + kNodes;                              // 400 KB
    int*   row_s   = cursor + kNodes;                             // 400 KB
    int*   partial = row_s + kNodes;                              // 2 KB
    int*   bucket  = partial + 512;                               // 6.4 MB

    hipMemsetAsync(count, 0, 2 * (size_t)kNodes * sizeof(int), stream);

    prep_w<<<32, 256, 0, stream>>>(Wn, Ws, Wstage);
    mfma_gemm<<<(kNodes + 127) / 128, 512, 0, stream>>>(X, Wstage, bs, h_srcb, out);

    const int eb = (kEdges + 255) / 256;
    hist<<<eb, 256, 0, stream>>>(dstp, count);
    chunk_sum<<<kNChunk, 256, 0, stream>>>(count, partial);
    scan_partial<<<1, 512, 0, stream>>>(partial);
    make_row_start<<<kNChunk, 256, 0, stream>>>(count, partial, row_s);
    scatter<<<eb, 256, 0, stream>>>(dstp, row_s, cursor, bucket);

    aggregate<<<(kNodes + 3) / 4, 256, 0, stream>>>(Xe, srcp, We, h_srcb,
                                                    count, row_s, bucket, out);
}

// Round 6
// 550.705 us; speedup vs baseline: 3.6333x; 1.0364x over previous
//
#include <hip/hip_runtime.h>
#include <stdint.h>

constexpr int kNodes = 100000;
constexpr int kEdges = 1600000;
constexpr int kDIn   = 256;
constexpr int kDEdge = 16;
constexpr int kDOut  = 128;

constexpr int kChunk  = 256;
constexpr int kNChunk = (kNodes + kChunk - 1) / kChunk;   // 391

typedef short  short8 __attribute__((ext_vector_type(8)));
typedef __bf16 bf16x8 __attribute__((ext_vector_type(8)));
typedef float  f32x4  __attribute__((ext_vector_type(4)));

union Frag { short8 s; bf16x8 b; };

static __device__ __forceinline__ float bflo(uint32_t u) {
    return __builtin_bit_cast(float, u << 16);
}
static __device__ __forceinline__ float bfhi(uint32_t u) {
    return __builtin_bit_cast(float, u & 0xFFFF0000u);
}

// ---- prep_w: W_neigh|W_self -> bf16, transposed to [n][k], pre-swizzled so the
// GEMM's B-staging is a LINEAR global_load_lds and the swizzled ds_read matches.
__global__ __launch_bounds__(256) void prep_w(const float* __restrict__ Wn,
                                              const float* __restrict__ Ws,
                                              char* __restrict__ Wstage)
{
    const int u = blockIdx.x * 256 + threadIdx.x;        // 8192 units
    const int n = u & 255, kc = (u >> 8) & 3, step = u >> 10;
    const float* wp = (n < kDOut) ? (Wn + n) : (Ws + (n - kDOut));
    const int k0 = step * 32 + kc * 8;
    short8 v;
    #pragma unroll
    for (int j = 0; j < 8; ++j)
        v[j] = __builtin_bit_cast(short, (__bf16)wp[(size_t)(k0 + j) * kDOut]);
    const int q = (n * 64 + kc * 16) ^ ((n & 7) << 4);
    *(short8*)(Wstage + (size_t)step * 16384 + q) = v;
}

// ---- mfma_gemm: h_src(bf16) = X @ Wn ; out(f32) = X @ Ws + b_self.
// 782 blocks x 512 threads (8 waves, 2Mx4N of 64x64). BM=128, BN=256, BK=32.
__global__ __launch_bounds__(512) void mfma_gemm(
    const float* __restrict__ X,
    const char*  __restrict__ Wstage,
    const float* __restrict__ bs,
    ushort* __restrict__ h_srcb,
    float* __restrict__ out)
{
    __shared__ char lds[24576];              // A: [0,8192)  B: [8192,24576)
    const int t    = threadIdx.x;
    const int lane = t & 63, wid = t >> 6;
    const int wr   = wid >> 2, wc = wid & 3;
    const int l15  = lane & 15;
    const int kb   = (lane >> 4) << 4;
    const long row0 = (long)blockIdx.x * 128;

    const int ar = t >> 2;
    const int as = t & 3;
    long arow = row0 + ar; if (arow > kNodes - 1) arow = kNodes - 1;
    const float4* xg = (const float4*)(X + arow * kDIn);
    char* aw = lds + ((ar * 64 + as * 16) ^ ((ar & 7) << 4));

    const int aswz   = (l15 & 7) << 4;
    const int addrA0 = ((wr * 64 + l15) * 64 + kb) ^ aswz;
    const int addrB0 = ((((wc * 64 + l15) * 64) + kb) ^ aswz) + 8192;

    f32x4 acc[4][4] = {};

    for (int step = 0; step < 8; ++step) {
        {
            const char* g = Wstage + (size_t)step * 16384 + wid * 2048 + lane * 16;
            char* l = lds + 8192 + wid * 2048;
            __builtin_amdgcn_global_load_lds(
                (const __attribute__((address_space(1))) uint32_t*)g,
                (__attribute__((address_space(3))) uint32_t*)l, 16, 0, 0);
            __builtin_amdgcn_global_load_lds(
                (const __attribute__((address_space(1))) uint32_t*)(g + 1024),
                (__attribute__((address_space(3))) uint32_t*)(l + 1024), 16, 0, 0);
        }
        const float4 f0 = xg[step * 8 + as * 2];
        const float4 f1 = xg[step * 8 + as * 2 + 1];
        bf16x8 av;
        av[0] = (__bf16)f0.x; av[1] = (__bf16)f0.y;
        av[2] = (__bf16)f0.z; av[3] = (__bf16)f0.w;
        av[4] = (__bf16)f1.x; av[5] = (__bf16)f1.y;
        av[6] = (__bf16)f1.z; av[7] = (__bf16)f1.w;
        *(bf16x8*)aw = av;
        __syncthreads();

        Frag af[4], bf[4];
        #pragma unroll
        for (int m = 0; m < 4; ++m) af[m].s = *(const short8*)(lds + addrA0 + m * 1024);
        #pragma unroll
        for (int n = 0; n < 4; ++n) bf[n].s = *(const short8*)(lds + addrB0 + n * 1024);
        #pragma unroll
        for (int m = 0; m < 4; ++m)
            #pragma unroll
            for (int n = 0; n < 4; ++n)
                acc[m][n] = __builtin_amdgcn_mfma_f32_16x16x32_bf16(af[m].b, bf[n].b, acc[m][n], 0, 0, 0);
        __syncthreads();
    }

    // epilogue: C/D layout col=lane&15, row=(lane>>4)*4+j
    const int rb = (lane >> 4) << 2;
    #pragma unroll
    for (int n = 0; n < 4; ++n) {
        const int col = wc * 64 + n * 16 + l15;          // [0,256)
        const bool selfh = (col >= kDOut);
        const int c = selfh ? (col - kDOut) : col;
        const float bias = selfh ? bs[c] : 0.0f;
        #pragma unroll
        for (int m = 0; m < 4; ++m) {
            const long r = row0 + wr * 64 + m * 16 + rb;
            #pragma unroll
            for (int j = 0; j < 4; ++j) {
                if (r + j < kNodes) {
                    if (selfh) out[(r + j) * kDOut + c] = acc[m][n][j] + bias;
                    else       h_srcb[(r + j) * kDOut + c] =
                                   __builtin_bit_cast(ushort, (__bf16)acc[m][n][j]);
                }
            }
        }
    }
}

// ---- CSR construction ----
__global__ __launch_bounds__(256) void hist(const int* __restrict__ dst,
                                            int* __restrict__ count)
{
    const int e = blockIdx.x * 256 + threadIdx.x;
    if (e < kEdges) atomicAdd(&count[dst[e]], 1);
}

__global__ __launch_bounds__(256) void chunk_sum(const int* __restrict__ count,
                                                 int* __restrict__ partial)
{
    __shared__ int s[256];
    const int i = blockIdx.x * 256 + threadIdx.x;
    s[threadIdx.x] = (i < kNodes) ? count[i] : 0;
    __syncthreads();
    for (int off = 128; off > 0; off >>= 1) {
        if (threadIdx.x < off) s[threadIdx.x] += s[threadIdx.x + off];
        __syncthreads();
    }
    if (threadIdx.x == 0) partial[blockIdx.x] = s[0];
}

__global__ __launch_bounds__(512) void scan_partial(int* __restrict__ partial)
{
    __shared__ int s[512];
    const int t = threadIdx.x;
    const int v = (t < kNChunk) ? partial[t] : 0;
    s[t] = v;
    __syncthreads();
    for (int off = 1; off < 512; off <<= 1) {
        const int u = (t >= off) ? s[t - off] : 0;
        __syncthreads();
        s[t] += u;
        __syncthreads();
    }
    if (t < kNChunk) partial[t] = s[t] - v;
}

__global__ __launch_bounds__(256) void make_row_start(const int* __restrict__ count,
                                                      const int* __restrict__ partial,
                                                      int* __restrict__ row_start)
{
    __shared__ int s[256];
    const int t = threadIdx.x;
    const int i = blockIdx.x * 256 + t;
    const int v = (i < kNodes) ? count[i] : 0;
    s[t] = v;
    __syncthreads();
    for (int off = 1; off < 256; off <<= 1) {
        const int u = (t >= off) ? s[t - off] : 0;
        __syncthreads();
        s[t] += u;
        __syncthreads();
    }
    if (i < kNodes) row_start[i] = partial[blockIdx.x] + s[t] - v;
}

// pack (src<<32)|e so aggregate's dependent chain skips the src[] gather
__global__ __launch_bounds__(256) void scatter(const int* __restrict__ dst,
                                               const int* __restrict__ src,
                                               const int* __restrict__ row_start,
                                               int* __restrict__ cursor,
                                               uint64_t* __restrict__ bucket64)
{
    const int e = blockIdx.x * 256 + threadIdx.x;
    if (e < kEdges) {
        const int d = dst[e];
        const int pos = row_start[d] + atomicAdd(&cursor[d], 1);
        bucket64[pos] = ((uint64_t)(uint32_t)src[e] << 32) | (uint32_t)e;
    }
}

// ---- aggregate: one wave per node. Per 16-edge batch: lanes 0..15 load the
// packed (src,e) pair; ALL 16 h_src gathers issue as one clause (hv[16],
// static indices) -> 16 outstanding loads/wave. Xe covered exactly once by the
// 64 lanes (edge lane>>2, chunk lane&3); We matvec applied once per node
// (linearity of segment-sum).
__global__ __launch_bounds__(256) void aggregate(
    const float*    __restrict__ Xe,
    const float*    __restrict__ We,
    const ushort*   __restrict__ h_srcb,
    const int*      __restrict__ count,
    const int*      __restrict__ row_start,
    const uint64_t* __restrict__ bucket64,
    float* __restrict__ out)
{
    const int lane = threadIdx.x & 63;
    const int wv   = threadIdx.x >> 6;
    const int c    = lane << 1;

    const int n = blockIdx.x * 4 + wv;
    if (n >= kNodes) return;
    const int deg = count[n];
    if (deg == 0) return;
    const int base = row_start[n];
    const int ch = (lane & 3) << 2;          // this lane's Xe chunk base k
    const int je = lane >> 2;                // this lane's edge slot for Xe

    float ax = 0.f, ay = 0.f;
    float4 xs{0.f, 0.f, 0.f, 0.f};

    const int nfull = deg >> 4;
    for (int b = 0; b < nfull; ++b) {
        const int i0 = b << 4;
        int e_l = 0, s_l = 0;
        if (lane < 16) {
            const uint64_t p = bucket64[base + i0 + lane];
            s_l = (int)(p >> 32);
            e_l = (int)(uint32_t)p;
        }
        {   // Xe sum: 16 edges x 4 chunks over 64 lanes
            const int eb = __shfl(e_l, je);
            const float4 x0 = *(const float4*)(Xe + (size_t)eb * kDEdge + ch);
            xs.x += x0.x; xs.y += x0.y; xs.z += x0.z; xs.w += x0.w;
        }
        uint32_t hv[16];
        #pragma unroll
        for (int j = 0; j < 16; ++j) {
            const int sj = __shfl(s_l, j);
            hv[j] = *(const uint32_t*)(h_srcb + (size_t)sj * kDOut + c);
        }
        #pragma unroll
        for (int j = 0; j < 16; ++j) {
            ax += bflo(hv[j]);
            ay += bfhi(hv[j]);
        }
    }

    const int rem = deg & 15;
    if (rem) {
        const int i0 = nfull << 4;
        int e_l = 0, s_l = 0;
        if (lane < rem) {
            const uint64_t p = bucket64[base + i0 + lane];
            s_l = (int)(p >> 32);
            e_l = (int)(uint32_t)p;
        }
        {
            const int eb = __shfl(e_l, je);
            const float4 x0 = *(const float4*)(Xe + (size_t)eb * kDEdge + ch);
            if (je < rem) { xs.x += x0.x; xs.y += x0.y; xs.z += x0.z; xs.w += x0.w; }
        }
        #pragma unroll
        for (int j = 0; j < 16; ++j) {
            if (j < rem) {
                const int sj = __shfl(s_l, j);
                const uint32_t h = *(const uint32_t*)(h_srcb + (size_t)sj * kDOut + c);
                ax += bflo(h);
                ay += bfhi(h);
            }
        }
    }

    // reduce xs over the 16 lanes sharing lane&3 (16 distinct edges per batch)
    #pragma unroll
    for (int mask = 4; mask < 64; mask <<= 1) {
        xs.x += __shfl_xor(xs.x, mask);
        xs.y += __shfl_xor(xs.y, mask);
        xs.z += __shfl_xor(xs.z, mask);
        xs.w += __shfl_xor(xs.w, mask);
    }
    // broadcast chunk q from lane q (lane q has lane&3 == q for q<4)
    float xesum[kDEdge];
    #pragma unroll
    for (int q = 0; q < 4; ++q) {
        xesum[q * 4 + 0] = __shfl(xs.x, q);
        xesum[q * 4 + 1] = __shfl(xs.y, q);
        xesum[q * 4 + 2] = __shfl(xs.z, q);
        xesum[q * 4 + 3] = __shfl(xs.w, q);
    }

    // one 16x128 matvec: p = (sum Xe) @ We, this lane's 2 cols
    float px = 0.f, py = 0.f;
    #pragma unroll
    for (int k = 0; k < kDEdge; ++k) {
        const float2 w = *(const float2*)(We + k * kDOut + c);
        px += xesum[k] * w.x;
        py += xesum[k] * w.y;
    }

    const float inv = 1.0f / (float)deg;
    float2* op = (float2*)(out + (size_t)n * kDOut + c);
    float2 o = *op;
    o.x += (ax + px) * inv;
    o.y += (ay + py) * inv;
    *op = o;
}

extern "C" void kernel_launch(void* const* d_in, const int* in_sizes, int n_in,
                              void* d_out, int out_size, void* d_ws, size_t ws_size,
                              hipStream_t stream)
{
    const float* X  = (const float*)d_in[0];
    const float* Xe = (const float*)d_in[1];
    const float* Wn = (const float*)d_in[2];
    const float* Ws = (const float*)d_in[3];
    const float* bs = (const float*)d_in[4];
    const float* We = (const float*)d_in[5];
    const int*   srcp = (const int*)d_in[6];
    const int*   dstp = (const int*)d_in[7];
    float* out = (float*)d_out;

    ushort* h_srcb = (ushort*)d_ws;                               // 25.6 MB
    char*  Wstage  = (char*)(h_srcb + (size_t)kNodes * kDOut);    // 128 KB
    int*   count   = (int*)(Wstage + 8 * 16384);                  // 400 KB
    int*   cursor  = count + kNodes;                              // 400 KB
    int*   row_s   = cursor + kNodes;                             // 400 KB
    int*   partial = row_s + kNodes;                              // 2 KB
    uint64_t* bucket64 = (uint64_t*)(partial + 512);              // 12.8 MB

    hipMemsetAsync(count, 0, 2 * (size_t)kNodes * sizeof(int), stream);

    prep_w<<<32, 256, 0, stream>>>(Wn, Ws, Wstage);
    mfma_gemm<<<(kNodes + 127) / 128, 512, 0, stream>>>(X, Wstage, bs, h_srcb, out);

    const int eb = (kEdges + 255) / 256;
    hist<<<eb, 256, 0, stream>>>(dstp, count);
    chunk_sum<<<kNChunk, 256, 0, stream>>>(count, partial);
    scan_partial<<<1, 512, 0, stream>>>(partial);
    make_row_start<<<kNChunk, 256, 0, stream>>>(count, partial, row_s);
    scatter<<<eb, 256, 0, stream>>>(dstp, srcp, row_s, cursor, bucket64);

    aggregate<<<(kNodes + 3) / 4, 256, 0, stream>>>(Xe, We, h_srcb,
                                                    count, row_s, bucket64, out);
}